// Round 5
// baseline (652.534 us; speedup 1.0000x reference)
//
#include <hip/hip_runtime.h>
#include <math.h>

#define NLINES 2048
#define WPL 32
#define EMBD 300
#define AD 400
#define NH 8
#define DPH 50
#define QKV_S 52
#define SC_S 36
#define BATCH 16
#define LPD 128
#define NCOLS 1200     // 3 proj * 400
#define NPAD 1280      // padded col count for Wt tables
#define WLINE_FL 39936 // per-line floats in word layout: 8*3*32*52
#define HBLK 4992      // per-(line,head) floats: 3*32*52

typedef __bf16 bf16;
typedef bf16  v8bf  __attribute__((ext_vector_type(8)));
typedef float v4f   __attribute__((ext_vector_type(4)));
typedef float v16f  __attribute__((ext_vector_type(16)));

__device__ __forceinline__ float elu(float x) {
    return x > 0.f ? x : expm1f(x);
}
__device__ __forceinline__ float elu_fast(float x) {
    return x > 0.f ? x : (__expf(x) - 1.f);
}

#define SCALE 7.0710678118654755f   // sqrt(50)

// ===========================================================================
// Split helpers: fp32 -> (hi, lo) bf16 pair, PACKED adjacent:
//   out[(row*(K2/8) + k/8)*16 + (k&7)]     = hi
//   out[(row*(K2/8) + k/8)*16 + 8 + (k&7)] = lo
// One MFMA fragment-pair (hi+lo, 32 B) lives in a single cacheline span.
// ===========================================================================
__global__ void split_rows_packed(const float* __restrict__ src,
                                  bf16* __restrict__ pk,
                                  int rows, int K, int K2)
{
    long idx = (long)blockIdx.x * 256 + threadIdx.x;
    if (idx >= (long)rows * K2) return;
    int r = (int)(idx / K2), k = (int)(idx - (long)r * K2);
    float x = (k < K) ? src[(long)r * K + k] : 0.f;
    bf16 h = (bf16)x;
    float hf = (float)h;
    bf16 l = (bf16)(x - hf);
    const long p = ((long)r * (K2 >> 3) + (k >> 3)) * 16 + (k & 7);
    pk[p] = h; pk[p + 8] = l;
}

// Weight tables fragment-packed + hi/lo adjacent:
//   out[((k>>3)*NPAD + n)*16 + (k&7)] = hi, +8 = lo.
// A wave's 32-col fragment-pair is 32 lanes x 32 B = 1 KB contiguous (L2 hit).
__global__ void split_wt_packed(const float* __restrict__ W0, const float* __restrict__ W1,
                                const float* __restrict__ W2,
                                const float* __restrict__ B0, const float* __restrict__ B1,
                                const float* __restrict__ B2,
                                bf16* __restrict__ pk,
                                float* __restrict__ biasCat, int K, int K2)
{
    long idx = (long)blockIdx.x * 256 + threadIdx.x;
    if (idx >= (long)NPAD * K2) return;
    int n = (int)(idx / K2), k = (int)(idx - (long)n * K2);
    float x = 0.f;
    if (k < K && n < NCOLS) {
        int p = n / 400, c = n - p * 400;
        const float* W = (p == 0) ? W0 : (p == 1) ? W1 : W2;
        x = W[(long)k * 400 + c];
    }
    bf16 h = (bf16)x;
    float hf = (float)h;
    bf16 l = (bf16)(x - hf);
    const long pidx = ((long)(k >> 3) * NPAD + n) * 16 + (k & 7);
    pk[pidx] = h; pk[pidx + 8] = l;
    if (k == 0) {
        float b = 0.f;
        if (n < NCOLS) {
            int p = n / 400, c = n - p * 400;
            const float* Bp = (p == 0) ? B0 : (p == 1) ? B1 : B2;
            b = Bp[c];
        }
        biasCat[n] = b;
    }
}

// ===========================================================================
// mfma_gemm: C = elu( A @ Wt^T + biasCat ), split-bf16 3-product.
// v6: NO LDS, NO K-loop barriers.  r1-r4 post-mortem: MfmaUtil pinned at
//     20-24% across four sync structures -> the block-wide barrier pair per
//     kt is the serializer (per-kt matrix work ~3.1K cyc/CU vs ~13.6K cyc
//     measured period).  A-reuse in-block is only 2x, so each wave gathers
//     its own A fragments global->VGPR (packed hi|lo, 32B/row/frag-pair);
//     B fragment-packed global->VGPR as in v5.  Waves are fully independent:
//     ~16 loads in flight each, latency hidden by 16 uncoupled waves/CU.
// Wave = 2x2 tiles of 32x32 (64x64 patch).  GRID: x = col-block (fastest).
// word_layout=1: C[(line*8+h)*3+p][32][52]; word_layout=0: row-major [row][1200].
// D layout (m74/m101): col=lane&31, row=(reg&3)+8*(reg>>2)+4*(lane>>5).
// ===========================================================================
__launch_bounds__(256, 4)
__global__ void mfma_gemm(const bf16* __restrict__ Ap,
                          const int* __restrict__ docs,
                          const bf16* __restrict__ Bp,
                          const float* __restrict__ biasCat,
                          float* __restrict__ C, int K2, int word_layout)
{
    __shared__ int tok[128];

    const int tid = threadIdx.x;

    // ---- XCD-chunked swizzle (bijective when total%8==0; identity otherwise)
    const int total = (int)(gridDim.x * gridDim.y);
    int flat = (int)(blockIdx.y * gridDim.x + blockIdx.x);   // HW dispatch order
    if ((total & 7) == 0) flat = (flat & 7) * (total >> 3) + (flat >> 3);
    const int bx = flat % (int)gridDim.x;
    const int by = flat / (int)gridDim.x;
    const int row0 = by * 128;     // row-block
    const int n0 = bx * 128;       // col-block

    if (tid < 128) tok[tid] = docs ? docs[row0 + tid] : (row0 + tid);
    __syncthreads();

    const int wv = tid >> 6, lane = tid & 63;
    const int half = lane >> 5, r32 = lane & 31;
    const int wm0 = (wv >> 1) * 64, wn0 = (wv & 1) * 64;

    const int colA = n0 + wn0 + r32;   // nt = 0 column for this lane
    const int colB = colA + 32;        // nt = 1

    // per-lane packed A row bases (elements); row stride = K2*2 bf16
    const long a0 = (long)tok[wm0 + r32]      * ((long)K2 * 2);
    const long a1 = (long)tok[wm0 + 32 + r32] * ((long)K2 * 2);

    v16f acc[2][2];
    #pragma unroll
    for (int a = 0; a < 2; ++a)
        #pragma unroll
        for (int b = 0; b < 2; ++b) acc[a][b] = (v16f)0.f;

    const int nk = K2 >> 5;          // BK = 32
    for (int kt = 0; kt < nk; ++kt) {
        #pragma unroll
        for (int ks = 0; ks < 2; ++ks) {
            const int k0 = kt * 32 + (ks * 2 + half) * 8;
            const bf16* bg = Bp + (long)(k0 >> 3) * NPAD * 16;
            const long ka = (long)k0 * 2;
            v8bf fb_h[2], fb_l[2], fa_h[2], fa_l[2];
            fb_h[0] = *(const v8bf*)&bg[(long)colA * 16];
            fb_l[0] = *(const v8bf*)&bg[(long)colA * 16 + 8];
            fb_h[1] = *(const v8bf*)&bg[(long)colB * 16];
            fb_l[1] = *(const v8bf*)&bg[(long)colB * 16 + 8];
            fa_h[0] = *(const v8bf*)&Ap[a0 + ka];
            fa_l[0] = *(const v8bf*)&Ap[a0 + ka + 8];
            fa_h[1] = *(const v8bf*)&Ap[a1 + ka];
            fa_l[1] = *(const v8bf*)&Ap[a1 + ka + 8];

            #pragma unroll
            for (int mt = 0; mt < 2; ++mt)
                #pragma unroll
                for (int nt = 0; nt < 2; ++nt)
                    acc[mt][nt] = __builtin_amdgcn_mfma_f32_32x32x16_bf16(fa_h[mt], fb_h[nt], acc[mt][nt], 0, 0, 0);
            #pragma unroll
            for (int mt = 0; mt < 2; ++mt)
                #pragma unroll
                for (int nt = 0; nt < 2; ++nt)
                    acc[mt][nt] = __builtin_amdgcn_mfma_f32_32x32x16_bf16(fa_h[mt], fb_l[nt], acc[mt][nt], 0, 0, 0);
            #pragma unroll
            for (int mt = 0; mt < 2; ++mt)
                #pragma unroll
                for (int nt = 0; nt < 2; ++nt)
                    acc[mt][nt] = __builtin_amdgcn_mfma_f32_32x32x16_bf16(fa_l[mt], fb_h[nt], acc[mt][nt], 0, 0, 0);
        }
    }

    // ---- epilogue: D col = lane&31, row = (rg&3)+8*(rg>>2)+4*half
    if (word_layout) {
        #pragma unroll
        for (int nt = 0; nt < 2; ++nt) {
            const int col = n0 + wn0 + nt * 32 + r32;
            if (col >= NCOLS) continue;
            const float bv = biasCat[col];
            const int p = col / 400;
            const int rem = col - p * 400;
            const int hh = rem / 50;
            const int d  = rem - hh * 50;
            #pragma unroll
            for (int mt = 0; mt < 2; ++mt) {
                const int rbase = row0 + wm0 + mt * 32 + 4 * half;
                #pragma unroll
                for (int rg = 0; rg < 16; ++rg) {
                    const int row = rbase + (rg & 3) + 8 * (rg >> 2);
                    const int ln = row >> 5, r = row & 31;
                    const long base = (((long)ln * NH + hh) * 3 + p) * 1664 + r * 52;
                    const float x = acc[mt][nt][rg] + bv;
                    C[base + d] = elu_fast(x);
                    if (d == 49) {   // fill layout holes -> full cachelines, and
                        float2 z; z.x = 0.f; z.y = 0.f;   // word_attn4 skips pad-zeroing
                        *(float2*)&C[base + 50] = z;
                    }
                }
            }
        }
    } else {
        #pragma unroll
        for (int nt = 0; nt < 2; ++nt) {
            const int col = n0 + wn0 + nt * 32 + r32;
            if (col >= NCOLS) continue;
            const float bv = biasCat[col];
            #pragma unroll
            for (int mt = 0; mt < 2; ++mt) {
                const int rbase = row0 + wm0 + mt * 32 + 4 * half;
                #pragma unroll
                for (int rg = 0; rg < 16; ++rg) {
                    const int row = rbase + (rg & 3) + 8 * (rg >> 2);
                    const float x = acc[mt][nt][rg] + bv;
                    C[(long)row * NCOLS + col] = elu_fast(x);
                }
            }
        }
    }
}

// ===========================================================================
// word_attn4: one 256-thread BLOCK per (line, head).  qkvw [line][h][3][32][52].
// Pads d=50,51 are zero-filled by the GEMM epilogue now (no LDS zeroing).
// ===========================================================================
__launch_bounds__(256)
__global__ void word_attn4(const float* __restrict__ qkvw, const int* __restrict__ docs,
                           const float* __restrict__ w_tgt,
                           float* __restrict__ line_e, float* __restrict__ mask_l)
{
    __shared__ __align__(16) float sh[HBLK];   // q[0..1663] k[1664..] v[3328..]
    __shared__ float sc[32 * 33];
    __shared__ float msk[WPL];
    __shared__ float tw[WPL];
    __shared__ float coefA[WPL];
    __shared__ float part[8][33];
    __shared__ float cw[WPL];
    __shared__ float vpart[4][64];
    __shared__ float tg[52];
    __shared__ float mls_s;

    const int tid = threadIdx.x;
    const int line = blockIdx.x >> 3;
    const int h = blockIdx.x & 7;

    if (tid < WPL) msk[tid] = (docs[line * WPL + tid] != 0) ? 1.f : 0.f;
    if (tid >= 64 && tid < 116) tg[tid - 64] = (tid - 64 < DPH) ? w_tgt[h * DPH + tid - 64] : 0.f;

    const float* src = qkvw + ((long)line * NH + h) * HBLK;
    for (int i = tid; i < HBLK / 4; i += 256)
        *(float4*)&sh[i * 4] = *(const float4*)&src[i * 4];
    __syncthreads();

    if (tid == 0) {
        float m = 0.f;
        for (int w = 0; w < WPL; ++w) m = fmaxf(m, msk[w]);
        mls_s = m;
        if (h == 0) mask_l[line] = m;
    }

    // ---- scores: thread (j = tid>>3, kg = tid&7) -> 4 scores
    const int j = tid >> 3, kg = tid & 7;
    float4 qv[13];
    #pragma unroll
    for (int i = 0; i < 13; ++i) qv[i] = *(const float4*)&sh[j * 52 + i * 4];

    float e4[4];
    float m = -1e30f;
    #pragma unroll
    for (int c = 0; c < 4; ++c) {
        const int kk = kg * 4 + c;
        const float* kr = &sh[1664 + kk * 52];
        float s = 0.f;
        #pragma unroll
        for (int i = 0; i < 13; ++i) {
            const float4 kv = *(const float4*)&kr[i * 4];
            s += qv[i].x * kv.x + qv[i].y * kv.y + qv[i].z * kv.z + qv[i].w * kv.w;
        }
        s = s / SCALE - 1e7f * (1.f - msk[kk]);
        e4[c] = s;
        m = fmaxf(m, s);
    }
    m = fmaxf(m, __shfl_xor(m, 1));
    m = fmaxf(m, __shfl_xor(m, 2));
    m = fmaxf(m, __shfl_xor(m, 4));
    float rsum = 0.f;
    #pragma unroll
    for (int c = 0; c < 4; ++c) { e4[c] = __expf(e4[c] - m); rsum += e4[c]; }
    rsum += __shfl_xor(rsum, 1);
    rsum += __shfl_xor(rsum, 2);
    rsum += __shfl_xor(rsum, 4);
    #pragma unroll
    for (int c = 0; c < 4; ++c) sc[j * 33 + kg * 4 + c] = e4[c];

    // ---- target softmax (wave-0 lanes 0..31)
    if (tid < WPL) {
        const float* kr = &sh[1664 + tid * 52];
        float s = 0.f;
        #pragma unroll
        for (int i = 0; i < 25; ++i)
            s += tg[2 * i] * kr[2 * i] + tg[2 * i + 1] * kr[2 * i + 1];
        s = s / SCALE - 1e7f * (1.f - msk[tid]);
        float tm = s;
        #pragma unroll
        for (int off = 16; off >= 1; off >>= 1) tm = fmaxf(tm, __shfl_xor(tm, off, 32));
        const float te = __expf(s - tm);
        float tsum = te;
        #pragma unroll
        for (int off = 16; off >= 1; off >>= 1) tsum += __shfl_xor(tsum, off, 32);
        tw[tid] = te / tsum;
    }
    __syncthreads();

    if (kg == 0) coefA[j] = tw[j] * msk[j] / rsum;
    __syncthreads();

    {
        const int k = tid & 31, jg = tid >> 5;
        float cv = 0.f;
        #pragma unroll
        for (int t = 0; t < 4; ++t) {
            const int jj = jg * 4 + t;
            cv += coefA[jj] * sc[jj * 33 + k];
        }
        part[jg][k] = cv;
    }
    __syncthreads();
    if (tid < WPL) {
        float cv = 0.f;
        #pragma unroll
        for (int g = 0; g < 8; ++g) cv += part[g][tid];
        cw[tid] = cv;
    }
    __syncthreads();

    {
        const int d = tid & 63, kh = tid >> 6;
        float acc = 0.f;
        if (d < 52) {
            #pragma unroll
            for (int t = 0; t < 8; ++t) {
                const int k = kh * 8 + t;
                acc += cw[k] * sh[3328 + k * 52 + d];
            }
        }
        vpart[kh][d] = acc;
    }
    __syncthreads();
    if (tid < DPH) {
        const float o = vpart[0][tid] + vpart[1][tid] + vpart[2][tid] + vpart[3][tid];
        line_e[(long)line * AD + h * DPH + tid] = o * mls_s;
    }
}

// ===========================================================================
// line_attn2: fully-parallel line attention + doc target attention.
// ===========================================================================
__launch_bounds__(256)
__global__ void line_attn2(const float* __restrict__ Q, const float* __restrict__ Kp,
                           const float* __restrict__ Vp,
                           long DS, long HS, long LS,
                           const float* __restrict__ l_tgt, const float* __restrict__ mask_l,
                           float* __restrict__ doc_e)
{
    __shared__ float kl[LPD * 52];     // 26624 B
    __shared__ float sc[64 * 130];     // 33280 B
    __shared__ float ml[LPD];
    __shared__ float tw[LPD];
    __shared__ float cw[LPD];
    __shared__ float coefA[64];
    __shared__ float pm[4 * 64];
    __shared__ float ps[4 * 64];
    __shared__ float tg[52];
    __shared__ float rr[2];
    __shared__ float vpart[2][64];

    const int tid = threadIdx.x;
    const int doc = blockIdx.x >> 3;
    const int h = blockIdx.x & 7;
    const float* qbase = Q + doc * DS + h * HS;
    const float* kbase = Kp + doc * DS + h * HS;
    const float* vbase = Vp + doc * DS + h * HS;

    if (tid < LPD) { ml[tid] = mask_l[doc * LPD + tid]; cw[tid] = 0.f; }
    if (tid < 52) tg[tid] = (tid < DPH) ? l_tgt[h * DPH + tid] : 0.f;
    for (int idx = tid; idx < LPD * 52; idx += 256) {
        const int r = idx / 52, d = idx - r * 52;
        kl[idx] = (d < DPH) ? kbase[(long)r * LS + d] : 0.f;
    }
    __syncthreads();

    if (tid < LPD) {
        const float* kr = &kl[tid * 52];
        float s = 0.f;
        #pragma unroll
        for (int i = 0; i < 25; ++i)
            s += tg[2 * i] * kr[2 * i] + tg[2 * i + 1] * kr[2 * i + 1];
        tw[tid] = s / SCALE - 1e7f * (1.f - ml[tid]);   // raw ts
    }
    __syncthreads();
    if (tid < 64) {
        float a = fmaxf(tw[tid], tw[64 + tid]);
        #pragma unroll
        for (int off = 32; off >= 1; off >>= 1) a = fmaxf(a, __shfl_xor(a, off));
        if (tid == 0) rr[0] = a;
    }
    __syncthreads();
    if (tid < 64) {
        const float tm2 = rr[0];
        float a = __expf(tw[tid] - tm2) + __expf(tw[64 + tid] - tm2);
        #pragma unroll
        for (int off = 32; off >= 1; off >>= 1) a += __shfl_xor(a, off);
        if (tid == 0) rr[1] = a;
    }
    __syncthreads();
    if (tid < LPD) tw[tid] = __expf(tw[tid] - rr[0]) / rr[1];   // final tw
    __syncthreads();

    const int j2 = tid & 63;
    const int kq = tid >> 6;          // 0..3, k range [kq*32, kq*32+32)

    for (int g = 0; g < 2; ++g) {
        const int j = g * 64 + j2;
        float2 qv[25];
        #pragma unroll
        for (int i = 0; i < 25; ++i)
            qv[i] = *(const float2*)(qbase + (long)j * LS + 2 * i);

        float m = -1e30f;
        for (int c = 0; c < 32; ++c) {
            const int k = kq * 32 + c;
            const float* kr = &kl[k * 52];
            float s = 0.f;
            #pragma unroll
            for (int i = 0; i < 25; ++i)
                s += qv[i].x * kr[2 * i] + qv[i].y * kr[2 * i + 1];
            s = s / SCALE - 1e7f * (1.f - ml[k]);
            sc[j2 * 130 + k] = s;
            m = fmaxf(m, s);
        }
        pm[kq * 64 + j2] = m;
        __syncthreads();
        const float rowm = fmaxf(fmaxf(pm[j2], pm[64 + j2]),
                                 fmaxf(pm[128 + j2], pm[192 + j2]));
        float sum = 0.f;
        for (int c = 0; c < 32; ++c) {
            const int k = kq * 32 + c;
            const float e = __expf(sc[j2 * 130 + k] - rowm);
            sc[j2 * 130 + k] = e;
            sum += e;
        }
        ps[kq * 64 + j2] = sum;
        __syncthreads();
        if (kq == 0) {
            const float rs = ps[j2] + ps[64 + j2] + ps[128 + j2] + ps[192 + j2];
            coefA[j2] = tw[j] * ml[j] / rs;
        }
        __syncthreads();
        if (tid < LPD) {
            float cv = 0.f;
            for (int jj = 0; jj < 64; ++jj)
                cv += coefA[jj] * sc[jj * 130 + tid];
            cw[tid] += cv;
        }
        __syncthreads();
    }

    const int d = tid & 63;
    const int half = (tid >> 6) & 1;
    if (tid < 128 && d < DPH) {
        float acc = 0.f;
        for (int k = half * 64; k < half * 64 + 64; ++k)
            acc += cw[k] * vbase[(long)k * LS + d];
        vpart[half][d] = acc;
    }
    __syncthreads();
    if (tid < DPH)
        doc_e[doc * AD + h * DPH + tid] = vpart[0][tid] + vpart[1][tid];
}

// ===========================================================================
// FALLBACK kernels (fp32 path)
// ===========================================================================
__launch_bounds__(256)
__global__ void word_attn(const float* __restrict__ qkv, const int* __restrict__ docs,
                          const float* __restrict__ w_tgt,
                          float* __restrict__ line_e, float* __restrict__ mask_l)
{
    __shared__ float qs[WPL * QKV_S];
    __shared__ float ks[WPL * QKV_S];
    __shared__ float vs[WPL * QKV_S];
    __shared__ float sc[WPL * SC_S];
    __shared__ float ts[WPL], tw[WPL], cw[WPL], msk[WPL];
    __shared__ float mls;

    const int tid = threadIdx.x;
    const int line = blockIdx.x;

    if (tid < WPL) msk[tid] = (docs[line * WPL + tid] != 0) ? 1.f : 0.f;
    __syncthreads();
    if (tid == 0) {
        float ml = 0.f;
        for (int w = 0; w < WPL; ++w) ml = fmaxf(ml, msk[w]);
        mls = ml;
        mask_l[line] = ml;
    }
    for (int h = 0; h < NH; ++h) {
        for (int idx = tid; idx < WPL * DPH; idx += 256) {
            const int r = idx / DPH, d = idx - r * DPH;
            const size_t base = (size_t)(line * WPL + r) * NCOLS + h * DPH + d;
            qs[r * QKV_S + d] = qkv[base];
            ks[r * QKV_S + d] = qkv[base + 400];
            vs[r * QKV_S + d] = qkv[base + 800];
        }
        __syncthreads();
        {
            const int j = tid >> 3, kg = tid & 7;
            #pragma unroll
            for (int c = 0; c < 4; ++c) {
                const int kk = kg * 4 + c;
                float s = 0.f;
                for (int dd = 0; dd < DPH; ++dd)
                    s += qs[j * QKV_S + dd] * ks[kk * QKV_S + dd];
                sc[j * SC_S + kk] = s / SCALE - 1e7f * (1.f - msk[kk]);
            }
        }
        if (tid < WPL) {
            float s = 0.f;
            for (int dd = 0; dd < DPH; ++dd)
                s += w_tgt[h * DPH + dd] * ks[tid * QKV_S + dd];
            ts[tid] = s / SCALE - 1e7f * (1.f - msk[tid]);
        }
        __syncthreads();
        if (tid < WPL) {
            const int j = tid;
            float m = -1e30f;
            for (int kk = 0; kk < WPL; ++kk) m = fmaxf(m, sc[j * SC_S + kk]);
            float sum = 0.f;
            for (int kk = 0; kk < WPL; ++kk) {
                const float e = expf(sc[j * SC_S + kk] - m);
                sc[j * SC_S + kk] = e;
                sum += e;
            }
            const float inv = 1.f / sum;
            for (int kk = 0; kk < WPL; ++kk) sc[j * SC_S + kk] *= inv;
        } else if (tid == WPL) {
            float m = -1e30f;
            for (int jj = 0; jj < WPL; ++jj) m = fmaxf(m, ts[jj]);
            float sum = 0.f;
            for (int jj = 0; jj < WPL; ++jj) { const float e = expf(ts[jj] - m); tw[jj] = e; sum += e; }
            const float inv = 1.f / sum;
            for (int jj = 0; jj < WPL; ++jj) tw[jj] *= inv;
        }
        __syncthreads();
        if (tid < WPL) {
            const int kk = tid;
            float c = 0.f;
            for (int jj = 0; jj < WPL; ++jj) c += tw[jj] * msk[jj] * sc[jj * SC_S + kk];
            cw[kk] = c;
        }
        __syncthreads();
        if (tid < DPH) {
            float acc = 0.f;
            for (int kk = 0; kk < WPL; ++kk) acc += cw[kk] * vs[kk * QKV_S + tid];
            line_e[line * AD + h * DPH + tid] = acc * mls;
        }
        __syncthreads();
    }
}

__launch_bounds__(256, 2)
__global__ void gemm_qkv(const float* __restrict__ Asrc,
                         const int* __restrict__ docs,
                         const float* __restrict__ emb,
                         const float* __restrict__ W0, const float* __restrict__ W1,
                         const float* __restrict__ W2,
                         const float* __restrict__ B0, const float* __restrict__ B1,
                         const float* __restrict__ B2,
                         float* __restrict__ C, int M, int K)
{
    __shared__ __align__(16) float As[32][132];
    __shared__ __align__(16) float Bs[32][132];

    const int tid = threadIdx.x;
    const int row0 = blockIdx.x * 128;
    const int n0 = blockIdx.y * 128;
    const int tc = tid & 15, tr = tid >> 4;

    float acc[2][2][4][4];
    #pragma unroll
    for (int a = 0; a < 2; ++a)
        #pragma unroll
        for (int b = 0; b < 2; ++b)
            #pragma unroll
            for (int c = 0; c < 4; ++c)
                #pragma unroll
                for (int d = 0; d < 4; ++d) acc[a][b][c][d] = 0.f;

    const int ma = tid & 127;
    const int kq = tid >> 7;
    const float* arow;
    if (docs) arow = emb + (size_t)docs[row0 + ma] * EMBD;
    else      arow = Asrc + (size_t)(row0 + ma) * K;

    const int gcol = n0 + ma;
    const int p = gcol / 400;
    const int ccol = gcol - p * 400;
    const float* Wp = (p == 0) ? W0 : (p == 1) ? W1 : W2;
    const bool colv = gcol < NCOLS;

    const int nk = (K + 31) >> 5;
    for (int ck = 0; ck < nk; ++ck) {
        const int k0 = ck * 32;
        #pragma unroll
        for (int f = 0; f < 4; ++f) {
            const int kl = kq * 16 + f * 4;
            const int kg = k0 + kl;
            float4 v = make_float4(0.f, 0.f, 0.f, 0.f);
            if (kg < K) v = *(const float4*)(arow + kg);
            As[kl + 0][ma] = v.x;
            As[kl + 1][ma] = v.y;
            As[kl + 2][ma] = v.z;
            As[kl + 3][ma] = v.w;
        }
        #pragma unroll
        for (int i = 0; i < 16; ++i) {
            const int kl = kq * 16 + i;
            const int kg = k0 + kl;
            float v = 0.f;
            if (colv && kg < K) v = Wp[(size_t)kg * 400 + ccol];
            Bs[kl][ma] = v;
        }
        __syncthreads();

        #pragma unroll 8
        for (int k = 0; k < 32; ++k) {
            const float4 a0 = *(const float4*)&As[k][tr * 4];
            const float4 a1 = *(const float4*)&As[k][64 + tr * 4];
            const float4 b0 = *(const float4*)&Bs[k][tc * 4];
            const float4 b1 = *(const float4*)&Bs[k][64 + tc * 4];
            const float ar[2][4] = {{a0.x, a0.y, a0.z, a0.w}, {a1.x, a1.y, a1.z, a1.w}};
            const float br[2][4] = {{b0.x, b0.y, b0.z, b0.w}, {b1.x, b1.y, b1.z, b1.w}};
            #pragma unroll
            for (int im = 0; im < 2; ++im)
                #pragma unroll
                for (int in_ = 0; in_ < 2; ++in_)
                    #pragma unroll
                    for (int rr = 0; rr < 4; ++rr)
                        #pragma unroll
                        for (int cc = 0; cc < 4; ++cc)
                            acc[im][in_][rr][cc] += ar[im][rr] * br[in_][cc];
        }
        __syncthreads();
    }

    #pragma unroll
    for (int in_ = 0; in_ < 2; ++in_) {
        const int ncol = n0 + in_ * 64 + tc * 4;
        if (ncol >= NCOLS) continue;
        const int pj = ncol / 400;
        const int cj = ncol - pj * 400;
        const float* Bp = (pj == 0) ? B0 : (pj == 1) ? B1 : B2;
        const float4 bv = *(const float4*)(Bp + cj);
        #pragma unroll
        for (int im = 0; im < 2; ++im) {
            #pragma unroll
            for (int rr = 0; rr < 4; ++rr) {
                const int row = row0 + im * 64 + tr * 4 + rr;
                float4 o;
                o.x = elu(acc[im][in_][rr][0] + bv.x);
                o.y = elu(acc[im][in_][rr][1] + bv.y);
                o.z = elu(acc[im][in_][rr][2] + bv.z);
                o.w = elu(acc[im][in_][rr][3] + bv.w);
                *(float4*)(C + (size_t)row * NCOLS + ncol) = o;
            }
        }
    }
}

__global__ void logits_kernel(const float* __restrict__ doc_e,
                              const float* __restrict__ fc1_w, const float* __restrict__ fc1_b,
                              const float* __restrict__ fc2_w, const float* __restrict__ fc2_b,
                              float* __restrict__ out)
{
    int o = blockIdx.x * blockDim.x + threadIdx.x;
    if (o >= BATCH * 582) return;
    int b = o / 582, jj = o - b * 582;
    const float* de = doc_e + b * AD;
    float acc;
    if (jj < 70) {
        acc = fc1_b[jj];
        for (int k = 0; k < AD; ++k) acc += de[k] * fc1_w[k * 70 + jj];
    } else {
        int j2 = jj - 70;
        acc = fc2_b[j2];
        for (int k = 0; k < AD; ++k) acc += de[k] * fc2_w[k * 512 + j2];
    }
    out[o] = acc;
}

// ---------------------------------------------------------------------------
extern "C" void kernel_launch(void* const* d_in, const int* in_sizes, int n_in,
                              void* d_out, int out_size, void* d_ws, size_t ws_size,
                              hipStream_t stream) {
    const int*   docs  = (const int*)  d_in[0];
    const float* emb   = (const float*)d_in[1];
    const float* wq_w  = (const float*)d_in[2];
    const float* wq_b  = (const float*)d_in[3];
    const float* wk_w  = (const float*)d_in[4];
    const float* wk_b  = (const float*)d_in[5];
    const float* wv_w  = (const float*)d_in[6];
    const float* wv_b  = (const float*)d_in[7];
    const float* w_tgt = (const float*)d_in[8];
    const float* lq_w  = (const float*)d_in[9];
    const float* lq_b  = (const float*)d_in[10];
    const float* lk_w  = (const float*)d_in[11];
    const float* lk_b  = (const float*)d_in[12];
    const float* lv_w  = (const float*)d_in[13];
    const float* lv_b  = (const float*)d_in[14];
    const float* l_tgt = (const float*)d_in[15];
    const float* fc1_w = (const float*)d_in[16];
    const float* fc1_b = (const float*)d_in[17];
    const float* fc2_w = (const float*)d_in[18];
    const float* fc2_b = (const float*)d_in[19];
    float* out = (float*)d_out;
    float* ws = (float*)d_ws;

    // Packed regions coalesce the old hi/lo pairs (same total bytes):
    //   EMB pack  @ O_EMB_H  : 30000*320*2 bf16 = 9.6M fl  -> ends O_WTW_H
    //   WTW pack  @ O_WTW_H  : 40*1280*16 bf16  = 409600 fl -> ends O_WTL_H
    //   WTL pack  @ O_WTL_H  : 52*1280*16 bf16  = 532480 fl -> ends O_LE_H
    //   LE  pack  @ O_LE_H   : 2048*416*2 bf16  = 851968 fl -> ends O_R
    const long O_LINE_E = 0;
    const long O_MASK_L = 819200;
    const long O_DOC_E  = 821248;
    const long O_BIAS_W = 827648;
    const long O_BIAS_L = 828928;
    const long O_EMB_H  = 830208;
    const long O_WTW_H  = 10430208;
    const long O_WTL_H  = 10839808;
    const long O_LE_H   = 11372288;
    const long O_R      = 12224256;

    const long LINE_QKV_FL = (long)NLINES * NCOLS;    // 2457600
    long ws_fl = (long)(ws_size / 4);
    long Rcap = ws_fl - O_R;

    if (Rcap >= LINE_QKV_FL) {
        // ================= MFMA fast path =================
        float* line_e = ws + O_LINE_E;
        float* mask_l = ws + O_MASK_L;
        float* doc_e  = ws + O_DOC_E;
        float* bias_w = ws + O_BIAS_W;
        float* bias_l = ws + O_BIAS_L;
        bf16* embp = (bf16*)(ws + O_EMB_H);
        bf16* wtwp = (bf16*)(ws + O_WTW_H);
        bf16* wtlp = (bf16*)(ws + O_WTL_H);
        bf16* lep  = (bf16*)(ws + O_LE_H);
        float* R   = ws + O_R;

        split_rows_packed<<<(30000L * 320 + 255) / 256, 256, 0, stream>>>(emb, embp, 30000, 300, 320);
        split_wt_packed<<<((long)NPAD * 320 + 255) / 256, 256, 0, stream>>>(wq_w, wk_w, wv_w,
                                                                            wq_b, wk_b, wv_b,
                                                                            wtwp, bias_w, 300, 320);
        split_wt_packed<<<((long)NPAD * 416 + 255) / 256, 256, 0, stream>>>(lq_w, lk_w, lv_w,
                                                                            lq_b, lk_b, lv_b,
                                                                            wtlp, bias_l, 400, 416);

        // chunk = 1024 lines (time-optimal per r5-r12 A/B)
        long maxl = Rcap / WLINE_FL;
        if (maxl > 1024) maxl = 1024;
        long chunk = (maxl / 4) * 4;
        if (chunk < 4) chunk = 4;
        for (long c0 = 0; c0 < NLINES; c0 += chunk) {
            long cl = NLINES - c0 < chunk ? NLINES - c0 : chunk;   // multiple of 4
            dim3 g1(10, (unsigned)((cl * 32) / 128));   // x=col (fastest), y=row
            mfma_gemm<<<g1, 256, 0, stream>>>(embp, docs + c0 * WPL,
                                              wtwp, bias_w, R, 320, 1);
            word_attn4<<<(unsigned)(cl * NH), 256, 0, stream>>>(R, docs + c0 * WPL, w_tgt,
                                                                line_e + c0 * AD, mask_l + c0);
        }

        split_rows_packed<<<((long)NLINES * 416 + 255) / 256, 256, 0, stream>>>(line_e, lep,
                                                                                NLINES, 400, 416);
        dim3 g2(10, NLINES / 128);
        mfma_gemm<<<g2, 256, 0, stream>>>(lep, nullptr, wtlp, bias_l, R, 416, 0);
        line_attn2<<<BATCH * NH, 256, 0, stream>>>(R, R + 400, R + 800,
                                                   (long)LPD * NCOLS, (long)DPH, (long)NCOLS,
                                                   l_tgt, mask_l, doc_e);
        logits_kernel<<<(BATCH * 582 + 255) / 256, 256, 0, stream>>>(doc_e, fc1_w, fc1_b,
                                                                     fc2_w, fc2_b, out);
    } else {
        // ================= fp32 fallback =================
        const long F_FIXED = 827648;
        const long PER_LINE_FL = (long)WPL * NCOLS;
        float* line_e = ws;
        float* mask_l = ws + 819200;
        float* doc_e  = ws + 821248;
        float* R      = ws + F_FIXED;
        long Rcap2 = ws_fl - F_FIXED;

        long maxl = Rcap2 / PER_LINE_FL;
        if (maxl > NLINES) maxl = NLINES;
        long maxl4 = (maxl / 4) * 4;
        int nc = (int)((NLINES + maxl4 - 1) / maxl4);
        int chunk = (int)((NLINES + nc - 1) / nc);
        chunk = ((chunk + 3) / 4) * 4;

        for (int c0 = 0; c0 < NLINES; c0 += chunk) {
            int cl = NLINES - c0 < chunk ? NLINES - c0 : chunk;
            dim3 g1((cl * 32) / 128, 10);
            gemm_qkv<<<g1, 256, 0, stream>>>(nullptr, docs + (size_t)c0 * WPL, emb,
                                             wq_w, wk_w, wv_w, wq_b, wk_b, wv_b,
                                             R, cl * 32, EMBD);
            word_attn<<<cl, 256, 0, stream>>>(R, docs + (size_t)c0 * WPL, w_tgt,
                                              line_e + (size_t)c0 * AD, mask_l + c0);
        }
        dim3 g2(16, 10);
        gemm_qkv<<<g2, 256, 0, stream>>>(line_e, nullptr, emb,
                                         lq_w, lk_w, lv_w, lq_b, lk_b, lv_b,
                                         R, NLINES, AD);
        line_attn2<<<BATCH * NH, 256, 0, stream>>>(R, R + 400, R + 800,
                                                   (long)LPD * NCOLS, (long)DPH, (long)NCOLS,
                                                   l_tgt, mask_l, doc_e);
        logits_kernel<<<(BATCH * 582 + 255) / 256, 256, 0, stream>>>(doc_e, fc1_w, fc1_b,
                                                                     fc2_w, fc2_b, out);
    }
}

// Round 6
// 561.060 us; speedup vs baseline: 1.1630x; 1.1630x over previous
//
#include <hip/hip_runtime.h>
#include <math.h>

#define NLINES 2048
#define WPL 32
#define EMBD 300
#define AD 400
#define NH 8
#define DPH 50
#define QKV_S 52
#define SC_S 36
#define BATCH 16
#define LPD 128
#define NCOLS 1200     // 3 proj * 400
#define NPAD 1280      // padded col count for Wt tables
#define HBLK 4992

typedef __bf16 bf16;
typedef bf16  v8bf  __attribute__((ext_vector_type(8)));
typedef float v16f  __attribute__((ext_vector_type(16)));

__device__ __forceinline__ float elu(float x) {
    return x > 0.f ? x : expm1f(x);
}
__device__ __forceinline__ float elu_fast(float x) {
    return x > 0.f ? x : (__expf(x) - 1.f);
}

#define SCALE 7.0710678118654755f   // sqrt(50)

// ===========================================================================
// Split helpers: fp32 -> (hi, lo) bf16 pair, PACKED adjacent:
//   out[(row*(K2/8) + k/8)*16 + (k&7)]     = hi
//   out[(row*(K2/8) + k/8)*16 + 8 + (k&7)] = lo
// ===========================================================================
__global__ void split_rows_packed(const float* __restrict__ src,
                                  bf16* __restrict__ pk,
                                  int rows, int K, int K2)
{
    long idx = (long)blockIdx.x * 256 + threadIdx.x;
    if (idx >= (long)rows * K2) return;
    int r = (int)(idx / K2), k = (int)(idx - (long)r * K2);
    float x = (k < K) ? src[(long)r * K + k] : 0.f;
    bf16 h = (bf16)x;
    float hf = (float)h;
    bf16 l = (bf16)(x - hf);
    const long p = ((long)r * (K2 >> 3) + (k >> 3)) * 16 + (k & 7);
    pk[p] = h; pk[p + 8] = l;
}

// Weight tables fragment-packed + hi/lo adjacent:
//   out[((k>>3)*NPAD + n)*16 + (k&7)] = hi, +8 = lo.
__global__ void split_wt_packed(const float* __restrict__ W0, const float* __restrict__ W1,
                                const float* __restrict__ W2,
                                const float* __restrict__ B0, const float* __restrict__ B1,
                                const float* __restrict__ B2,
                                bf16* __restrict__ pk,
                                float* __restrict__ biasCat, int K, int K2)
{
    long idx = (long)blockIdx.x * 256 + threadIdx.x;
    if (idx >= (long)NPAD * K2) return;
    int n = (int)(idx / K2), k = (int)(idx - (long)n * K2);
    float x = 0.f;
    if (k < K && n < NCOLS) {
        int p = n / 400, c = n - p * 400;
        const float* W = (p == 0) ? W0 : (p == 1) ? W1 : W2;
        x = W[(long)k * 400 + c];
    }
    bf16 h = (bf16)x;
    float hf = (float)h;
    bf16 l = (bf16)(x - hf);
    const long pidx = ((long)(k >> 3) * NPAD + n) * 16 + (k & 7);
    pk[pidx] = h; pk[pidx + 8] = l;
    if (k == 0) {
        float b = 0.f;
        if (n < NCOLS) {
            int p = n / 400, c = n - p * 400;
            const float* Bp = (p == 0) ? B0 : (p == 1) ? B1 : B2;
            b = Bp[c];
        }
        biasCat[n] = b;
    }
}

// ===========================================================================
// fused_word: one 512-thread block per LINE.  QKV GEMM (split-bf16, MFMA)
// lands in LDS; word attention (verified word_attn4 math) runs in-LDS; only
// line_e (400 f) leaves the block.  Eliminates the 328+ MB R round-trip and
// all word_attn4 dispatches (r5 post-mortem: unfused GEMM latency-bound at
// ~20-24% MfmaUtil across 5 sync structures; fusion attacks the pipeline).
// 2 passes of 4 heads (QKV f32 LDS = 80 KB/pass); attention runs 2 heads in
// parallel (thread halves).  A (32 token rows, packed hi|lo) staged once.
// ===========================================================================
__launch_bounds__(512, 1)
__global__ void fused_word(const bf16* __restrict__ Ap,   // emb packed [row][40][hi8|lo8]
                           const int* __restrict__ docs,
                           const bf16* __restrict__ Bp,   // wtw packed [kf][NPAD][hi8|lo8]
                           const float* __restrict__ biasCat,
                           const float* __restrict__ w_tgt,
                           float* __restrict__ line_e, float* __restrict__ mask_l)
{
    __shared__ __align__(16) bf16 Alds[40 * 2 * 32 * 8];     // [kf][hl][row][8]  40 KB
    __shared__ __align__(16) float qkv[3][4][32][52];        // pass-local        79.9 KB
    __shared__ float sc2[2][32 * 33];
    __shared__ float tw2[2][WPL];
    __shared__ float coefA2[2][WPL];
    __shared__ float part2[2][8][33];
    __shared__ float cw2[2][WPL];
    __shared__ float vpart2[2][4][64];
    __shared__ float tg2[2][52];
    __shared__ float msk[WPL];
    __shared__ float mls_s;

    const int tid = threadIdx.x;
    const int line = blockIdx.x;

    if (tid < WPL) msk[tid] = (docs[line * WPL + tid] != 0) ? 1.f : 0.f;
    __syncthreads();
    if (tid == 0) {
        float m = 0.f;
        for (int w = 0; w < WPL; ++w) m = fmaxf(m, msk[w]);
        mls_s = m;
        mask_l[line] = m;
    }

    // ---- stage A once: slot = (kf*2+hl)*32 + row, 16B/slot, k-major in LDS
    for (int slot = tid; slot < 40 * 2 * 32; slot += 512) {
        const int row = slot & 31;
        const int hl  = (slot >> 5) & 1;
        const int kf  = slot >> 6;
        const int token = docs[line * WPL + row];
        *(v8bf*)&Alds[slot * 8] = *(const v8bf*)&Ap[((long)token * 40 + kf) * 16 + hl * 8];
    }

    const int wv = tid >> 6;           // 0..7
    const int lane = tid & 63;
    const int half = lane >> 5, r32 = lane & 31;
    const int sub = tid >> 8;          // attention head-parallel half
    const int t2  = tid & 255;

    for (int ph = 0; ph < 2; ++ph) {
        const int h0 = ph * 4;

        for (int i = tid; i < 3 * 4 * 32 * 52; i += 512)
            ((float*)qkv)[i] = 0.f;
        __syncthreads();               // A staged (ph0) + qkv zeroed

        // ---- GEMM: 21 col-tiles (7 per proj, 32 cols each, covering the 4
        // heads of this pass).  Wave wv owns tiles {wv, wv+8, wv+16} run as 3
        // concurrent acc chains (ILP for the MFMA pipe); third duplicates the
        // second when out of range (benign same-value rewrite).
        {
            const int ta = wv;
            const int tb = wv + 8;
            const bool has3 = (wv + 16) < 21;
            const int tc = has3 ? wv + 16 : tb;
            const int c0a = (ta / 7) * 400 + (ph * 6 + ta % 7) * 32;
            const int c0b = (tb / 7) * 400 + (ph * 6 + tb % 7) * 32;
            const int c0c = (tc / 7) * 400 + (ph * 6 + tc % 7) * 32;

            v16f a0 = (v16f)0.f, a1 = (v16f)0.f, a2 = (v16f)0.f;
            #pragma unroll 4
            for (int s = 0; s < 20; ++s) {
                const int kf = 2 * s + half;
                const v8bf fah = *(const v8bf*)&Alds[((kf * 2 + 0) * 32 + r32) * 8];
                const v8bf fal = *(const v8bf*)&Alds[((kf * 2 + 1) * 32 + r32) * 8];
                const bf16* bg = Bp + (long)kf * NPAD * 16;
                const v8bf fbh0 = *(const v8bf*)&bg[(c0a + r32) * 16];
                const v8bf fbl0 = *(const v8bf*)&bg[(c0a + r32) * 16 + 8];
                const v8bf fbh1 = *(const v8bf*)&bg[(c0b + r32) * 16];
                const v8bf fbl1 = *(const v8bf*)&bg[(c0b + r32) * 16 + 8];
                const v8bf fbh2 = *(const v8bf*)&bg[(c0c + r32) * 16];
                const v8bf fbl2 = *(const v8bf*)&bg[(c0c + r32) * 16 + 8];
                a0 = __builtin_amdgcn_mfma_f32_32x32x16_bf16(fah, fbh0, a0, 0, 0, 0);
                a1 = __builtin_amdgcn_mfma_f32_32x32x16_bf16(fah, fbh1, a1, 0, 0, 0);
                a2 = __builtin_amdgcn_mfma_f32_32x32x16_bf16(fah, fbh2, a2, 0, 0, 0);
                a0 = __builtin_amdgcn_mfma_f32_32x32x16_bf16(fah, fbl0, a0, 0, 0, 0);
                a1 = __builtin_amdgcn_mfma_f32_32x32x16_bf16(fah, fbl1, a1, 0, 0, 0);
                a2 = __builtin_amdgcn_mfma_f32_32x32x16_bf16(fah, fbl2, a2, 0, 0, 0);
                a0 = __builtin_amdgcn_mfma_f32_32x32x16_bf16(fal, fbh0, a0, 0, 0, 0);
                a1 = __builtin_amdgcn_mfma_f32_32x32x16_bf16(fal, fbh1, a1, 0, 0, 0);
                a2 = __builtin_amdgcn_mfma_f32_32x32x16_bf16(fal, fbh2, a2, 0, 0, 0);
            }

            // epilogue: D col = lane&31 (=r32), row = (rg&3)+8*(rg>>2)+4*half
            const v16f* accs[3] = { &a0, &a1, &a2 };
            const int   c0s[3]  = { c0a, c0b, c0c };
            #pragma unroll
            for (int u = 0; u < 3; ++u) {
                const int col = c0s[u] + r32;
                const int p = col / 400;
                const int rem = col - p * 400;
                const int hh = rem / 50;
                if (rem < 400 && hh >= h0 && hh < h0 + 4) {
                    const int d = rem - hh * 50;
                    const float bv = biasCat[col];
                    const v16f& a = *accs[u];
                    #pragma unroll
                    for (int rg = 0; rg < 16; ++rg) {
                        const int row = (rg & 3) + 8 * (rg >> 2) + 4 * half;
                        qkv[p][hh - h0][row][d] = elu_fast(a[rg] + bv);
                    }
                }
            }
        }
        __syncthreads();

        // ---- attention: 2 heads in parallel (sub = tid>>8), 2 rounds
        for (int hp = 0; hp < 2; ++hp) {
            const int hl = hp * 2 + sub;       // 0..3
            const int h  = h0 + hl;
            const float* q  = &qkv[0][hl][0][0];
            const float* kk_ = &qkv[1][hl][0][0];
            const float* vv_ = &qkv[2][hl][0][0];

            if (t2 < 52) tg2[sub][t2] = (t2 < DPH) ? w_tgt[h * DPH + t2] : 0.f;
            __syncthreads();

            const int j = t2 >> 3, kg = t2 & 7;
            float4 qv[13];
            #pragma unroll
            for (int i = 0; i < 13; ++i) qv[i] = *(const float4*)&q[j * 52 + i * 4];

            float e4[4];
            float m = -1e30f;
            #pragma unroll
            for (int c = 0; c < 4; ++c) {
                const int kk = kg * 4 + c;
                const float* kr = &kk_[kk * 52];
                float s = 0.f;
                #pragma unroll
                for (int i = 0; i < 13; ++i) {
                    const float4 kv = *(const float4*)&kr[i * 4];
                    s += qv[i].x * kv.x + qv[i].y * kv.y + qv[i].z * kv.z + qv[i].w * kv.w;
                }
                s = s / SCALE - 1e7f * (1.f - msk[kk]);
                e4[c] = s;
                m = fmaxf(m, s);
            }
            m = fmaxf(m, __shfl_xor(m, 1));
            m = fmaxf(m, __shfl_xor(m, 2));
            m = fmaxf(m, __shfl_xor(m, 4));
            float rsum = 0.f;
            #pragma unroll
            for (int c = 0; c < 4; ++c) { e4[c] = __expf(e4[c] - m); rsum += e4[c]; }
            rsum += __shfl_xor(rsum, 1);
            rsum += __shfl_xor(rsum, 2);
            rsum += __shfl_xor(rsum, 4);
            #pragma unroll
            for (int c = 0; c < 4; ++c) sc2[sub][j * 33 + kg * 4 + c] = e4[c];

            if (t2 < WPL) {   // target softmax
                const float* kr = &kk_[t2 * 52];
                float s = 0.f;
                #pragma unroll
                for (int i = 0; i < 25; ++i)
                    s += tg2[sub][2 * i] * kr[2 * i] + tg2[sub][2 * i + 1] * kr[2 * i + 1];
                s = s / SCALE - 1e7f * (1.f - msk[t2]);
                float tm = s;
                #pragma unroll
                for (int off = 16; off >= 1; off >>= 1) tm = fmaxf(tm, __shfl_xor(tm, off, 32));
                const float te = __expf(s - tm);
                float tsum = te;
                #pragma unroll
                for (int off = 16; off >= 1; off >>= 1) tsum += __shfl_xor(tsum, off, 32);
                tw2[sub][t2] = te / tsum;
            }
            __syncthreads();

            if (kg == 0) coefA2[sub][j] = tw2[sub][j] * msk[j] / rsum;
            __syncthreads();

            {
                const int k = t2 & 31, jg = t2 >> 5;
                float cv = 0.f;
                #pragma unroll
                for (int t = 0; t < 4; ++t) {
                    const int jj = jg * 4 + t;
                    cv += coefA2[sub][jj] * sc2[sub][jj * 33 + k];
                }
                part2[sub][jg][k] = cv;
            }
            __syncthreads();
            if (t2 < WPL) {
                float cv = 0.f;
                #pragma unroll
                for (int g = 0; g < 8; ++g) cv += part2[sub][g][t2];
                cw2[sub][t2] = cv;
            }
            __syncthreads();

            {
                const int d = t2 & 63, kh = t2 >> 6;
                float acc = 0.f;
                if (d < 52) {
                    #pragma unroll
                    for (int t = 0; t < 8; ++t) {
                        const int k = kh * 8 + t;
                        acc += cw2[sub][k] * vv_[k * 52 + d];
                    }
                }
                vpart2[sub][kh][d] = acc;
            }
            __syncthreads();
            if (t2 < DPH) {
                const float o = vpart2[sub][0][t2] + vpart2[sub][1][t2]
                              + vpart2[sub][2][t2] + vpart2[sub][3][t2];
                line_e[(long)line * AD + h * DPH + t2] = o * mls_s;
            }
            __syncthreads();
        }
    }
}

// ===========================================================================
// mfma_gemm (line-level only): C = elu( A @ Wt^T + biasCat ), split-bf16,
// barrier-free per-wave global gather (v6) — adequate for the small line GEMM.
// ===========================================================================
__launch_bounds__(256, 4)
__global__ void mfma_gemm(const bf16* __restrict__ Ap,
                          const int* __restrict__ docs,
                          const bf16* __restrict__ Bp,
                          const float* __restrict__ biasCat,
                          float* __restrict__ C, int K2, int word_layout)
{
    __shared__ int tok[128];

    const int tid = threadIdx.x;

    const int total = (int)(gridDim.x * gridDim.y);
    int flat = (int)(blockIdx.y * gridDim.x + blockIdx.x);
    if ((total & 7) == 0) flat = (flat & 7) * (total >> 3) + (flat >> 3);
    const int bx = flat % (int)gridDim.x;
    const int by = flat / (int)gridDim.x;
    const int row0 = by * 128;
    const int n0 = bx * 128;

    if (tid < 128) tok[tid] = docs ? docs[row0 + tid] : (row0 + tid);
    __syncthreads();

    const int wv = tid >> 6, lane = tid & 63;
    const int half = lane >> 5, r32 = lane & 31;
    const int wm0 = (wv >> 1) * 64, wn0 = (wv & 1) * 64;

    const int colA = n0 + wn0 + r32;
    const int colB = colA + 32;

    const long a0 = (long)tok[wm0 + r32]      * ((long)K2 * 2);
    const long a1 = (long)tok[wm0 + 32 + r32] * ((long)K2 * 2);

    v16f acc[2][2];
    #pragma unroll
    for (int a = 0; a < 2; ++a)
        #pragma unroll
        for (int b = 0; b < 2; ++b) acc[a][b] = (v16f)0.f;

    const int nk = K2 >> 5;
    for (int kt = 0; kt < nk; ++kt) {
        #pragma unroll
        for (int ks = 0; ks < 2; ++ks) {
            const int k0 = kt * 32 + (ks * 2 + half) * 8;
            const bf16* bg = Bp + (long)(k0 >> 3) * NPAD * 16;
            const long ka = (long)k0 * 2;
            v8bf fb_h[2], fb_l[2], fa_h[2], fa_l[2];
            fb_h[0] = *(const v8bf*)&bg[(long)colA * 16];
            fb_l[0] = *(const v8bf*)&bg[(long)colA * 16 + 8];
            fb_h[1] = *(const v8bf*)&bg[(long)colB * 16];
            fb_l[1] = *(const v8bf*)&bg[(long)colB * 16 + 8];
            fa_h[0] = *(const v8bf*)&Ap[a0 + ka];
            fa_l[0] = *(const v8bf*)&Ap[a0 + ka + 8];
            fa_h[1] = *(const v8bf*)&Ap[a1 + ka];
            fa_l[1] = *(const v8bf*)&Ap[a1 + ka + 8];

            #pragma unroll
            for (int mt = 0; mt < 2; ++mt)
                #pragma unroll
                for (int nt = 0; nt < 2; ++nt)
                    acc[mt][nt] = __builtin_amdgcn_mfma_f32_32x32x16_bf16(fa_h[mt], fb_h[nt], acc[mt][nt], 0, 0, 0);
            #pragma unroll
            for (int mt = 0; mt < 2; ++mt)
                #pragma unroll
                for (int nt = 0; nt < 2; ++nt)
                    acc[mt][nt] = __builtin_amdgcn_mfma_f32_32x32x16_bf16(fa_h[mt], fb_l[nt], acc[mt][nt], 0, 0, 0);
            #pragma unroll
            for (int mt = 0; mt < 2; ++mt)
                #pragma unroll
                for (int nt = 0; nt < 2; ++nt)
                    acc[mt][nt] = __builtin_amdgcn_mfma_f32_32x32x16_bf16(fa_l[mt], fb_h[nt], acc[mt][nt], 0, 0, 0);
        }
    }

    if (word_layout) {
        #pragma unroll
        for (int nt = 0; nt < 2; ++nt) {
            const int col = n0 + wn0 + nt * 32 + r32;
            if (col >= NCOLS) continue;
            const float bv = biasCat[col];
            const int p = col / 400;
            const int rem = col - p * 400;
            const int hh = rem / 50;
            const int d  = rem - hh * 50;
            #pragma unroll
            for (int mt = 0; mt < 2; ++mt) {
                const int rbase = row0 + wm0 + mt * 32 + 4 * half;
                #pragma unroll
                for (int rg = 0; rg < 16; ++rg) {
                    const int row = rbase + (rg & 3) + 8 * (rg >> 2);
                    const int ln = row >> 5, r = row & 31;
                    const long base = (((long)ln * NH + hh) * 3 + p) * 1664 + r * 52;
                    const float x = acc[mt][nt][rg] + bv;
                    C[base + d] = elu_fast(x);
                    if (d == 49) {
                        float2 z; z.x = 0.f; z.y = 0.f;
                        *(float2*)&C[base + 50] = z;
                    }
                }
            }
        }
    } else {
        #pragma unroll
        for (int nt = 0; nt < 2; ++nt) {
            const int col = n0 + wn0 + nt * 32 + r32;
            if (col >= NCOLS) continue;
            const float bv = biasCat[col];
            #pragma unroll
            for (int mt = 0; mt < 2; ++mt) {
                const int rbase = row0 + wm0 + mt * 32 + 4 * half;
                #pragma unroll
                for (int rg = 0; rg < 16; ++rg) {
                    const int row = rbase + (rg & 3) + 8 * (rg >> 2);
                    const float x = acc[mt][nt][rg] + bv;
                    C[(long)row * NCOLS + col] = elu_fast(x);
                }
            }
        }
    }
}

// ===========================================================================
// line_attn2: fully-parallel line attention + doc target attention.
// ===========================================================================
__launch_bounds__(256)
__global__ void line_attn2(const float* __restrict__ Q, const float* __restrict__ Kp,
                           const float* __restrict__ Vp,
                           long DS, long HS, long LS,
                           const float* __restrict__ l_tgt, const float* __restrict__ mask_l,
                           float* __restrict__ doc_e)
{
    __shared__ float kl[LPD * 52];
    __shared__ float sc[64 * 130];
    __shared__ float ml[LPD];
    __shared__ float tw[LPD];
    __shared__ float cw[LPD];
    __shared__ float coefA[64];
    __shared__ float pm[4 * 64];
    __shared__ float ps[4 * 64];
    __shared__ float tg[52];
    __shared__ float rr[2];
    __shared__ float vpart[2][64];

    const int tid = threadIdx.x;
    const int doc = blockIdx.x >> 3;
    const int h = blockIdx.x & 7;
    const float* qbase = Q + doc * DS + h * HS;
    const float* kbase = Kp + doc * DS + h * HS;
    const float* vbase = Vp + doc * DS + h * HS;

    if (tid < LPD) { ml[tid] = mask_l[doc * LPD + tid]; cw[tid] = 0.f; }
    if (tid < 52) tg[tid] = (tid < DPH) ? l_tgt[h * DPH + tid] : 0.f;
    for (int idx = tid; idx < LPD * 52; idx += 256) {
        const int r = idx / 52, d = idx - r * 52;
        kl[idx] = (d < DPH) ? kbase[(long)r * LS + d] : 0.f;
    }
    __syncthreads();

    if (tid < LPD) {
        const float* kr = &kl[tid * 52];
        float s = 0.f;
        #pragma unroll
        for (int i = 0; i < 25; ++i)
            s += tg[2 * i] * kr[2 * i] + tg[2 * i + 1] * kr[2 * i + 1];
        tw[tid] = s / SCALE - 1e7f * (1.f - ml[tid]);
    }
    __syncthreads();
    if (tid < 64) {
        float a = fmaxf(tw[tid], tw[64 + tid]);
        #pragma unroll
        for (int off = 32; off >= 1; off >>= 1) a = fmaxf(a, __shfl_xor(a, off));
        if (tid == 0) rr[0] = a;
    }
    __syncthreads();
    if (tid < 64) {
        const float tm2 = rr[0];
        float a = __expf(tw[tid] - tm2) + __expf(tw[64 + tid] - tm2);
        #pragma unroll
        for (int off = 32; off >= 1; off >>= 1) a += __shfl_xor(a, off);
        if (tid == 0) rr[1] = a;
    }
    __syncthreads();
    if (tid < LPD) tw[tid] = __expf(tw[tid] - rr[0]) / rr[1];
    __syncthreads();

    const int j2 = tid & 63;
    const int kq = tid >> 6;

    for (int g = 0; g < 2; ++g) {
        const int j = g * 64 + j2;
        float2 qv[25];
        #pragma unroll
        for (int i = 0; i < 25; ++i)
            qv[i] = *(const float2*)(qbase + (long)j * LS + 2 * i);

        float m = -1e30f;
        for (int c = 0; c < 32; ++c) {
            const int k = kq * 32 + c;
            const float* kr = &kl[k * 52];
            float s = 0.f;
            #pragma unroll
            for (int i = 0; i < 25; ++i)
                s += qv[i].x * kr[2 * i] + qv[i].y * kr[2 * i + 1];
            s = s / SCALE - 1e7f * (1.f - ml[k]);
            sc[j2 * 130 + k] = s;
            m = fmaxf(m, s);
        }
        pm[kq * 64 + j2] = m;
        __syncthreads();
        const float rowm = fmaxf(fmaxf(pm[j2], pm[64 + j2]),
                                 fmaxf(pm[128 + j2], pm[192 + j2]));
        float sum = 0.f;
        for (int c = 0; c < 32; ++c) {
            const int k = kq * 32 + c;
            const float e = __expf(sc[j2 * 130 + k] - rowm);
            sc[j2 * 130 + k] = e;
            sum += e;
        }
        ps[kq * 64 + j2] = sum;
        __syncthreads();
        if (kq == 0) {
            const float rs = ps[j2] + ps[64 + j2] + ps[128 + j2] + ps[192 + j2];
            coefA[j2] = tw[j] * ml[j] / rs;
        }
        __syncthreads();
        if (tid < LPD) {
            float cv = 0.f;
            for (int jj = 0; jj < 64; ++jj)
                cv += coefA[jj] * sc[jj * 130 + tid];
            cw[tid] += cv;
        }
        __syncthreads();
    }

    const int d = tid & 63;
    const int half = (tid >> 6) & 1;
    if (tid < 128 && d < DPH) {
        float acc = 0.f;
        for (int k = half * 64; k < half * 64 + 64; ++k)
            acc += cw[k] * vbase[(long)k * LS + d];
        vpart[half][d] = acc;
    }
    __syncthreads();
    if (tid < DPH)
        doc_e[doc * AD + h * DPH + tid] = vpart[0][tid] + vpart[1][tid];
}

// ===========================================================================
// FALLBACK kernels (fp32 path)
// ===========================================================================
__launch_bounds__(256)
__global__ void word_attn(const float* __restrict__ qkv, const int* __restrict__ docs,
                          const float* __restrict__ w_tgt,
                          float* __restrict__ line_e, float* __restrict__ mask_l)
{
    __shared__ float qs[WPL * QKV_S];
    __shared__ float ks[WPL * QKV_S];
    __shared__ float vs[WPL * QKV_S];
    __shared__ float sc[WPL * SC_S];
    __shared__ float ts[WPL], tw[WPL], cw[WPL], msk[WPL];
    __shared__ float mls;

    const int tid = threadIdx.x;
    const int line = blockIdx.x;

    if (tid < WPL) msk[tid] = (docs[line * WPL + tid] != 0) ? 1.f : 0.f;
    __syncthreads();
    if (tid == 0) {
        float ml = 0.f;
        for (int w = 0; w < WPL; ++w) ml = fmaxf(ml, msk[w]);
        mls = ml;
        mask_l[line] = ml;
    }
    for (int h = 0; h < NH; ++h) {
        for (int idx = tid; idx < WPL * DPH; idx += 256) {
            const int r = idx / DPH, d = idx - r * DPH;
            const size_t base = (size_t)(line * WPL + r) * NCOLS + h * DPH + d;
            qs[r * QKV_S + d] = qkv[base];
            ks[r * QKV_S + d] = qkv[base + 400];
            vs[r * QKV_S + d] = qkv[base + 800];
        }
        __syncthreads();
        {
            const int j = tid >> 3, kg = tid & 7;
            #pragma unroll
            for (int c = 0; c < 4; ++c) {
                const int kk = kg * 4 + c;
                float s = 0.f;
                for (int dd = 0; dd < DPH; ++dd)
                    s += qs[j * QKV_S + dd] * ks[kk * QKV_S + dd];
                sc[j * SC_S + kk] = s / SCALE - 1e7f * (1.f - msk[kk]);
            }
        }
        if (tid < WPL) {
            float s = 0.f;
            for (int dd = 0; dd < DPH; ++dd)
                s += w_tgt[h * DPH + dd] * ks[tid * QKV_S + dd];
            ts[tid] = s / SCALE - 1e7f * (1.f - msk[tid]);
        }
        __syncthreads();
        if (tid < WPL) {
            const int j = tid;
            float m = -1e30f;
            for (int kk = 0; kk < WPL; ++kk) m = fmaxf(m, sc[j * SC_S + kk]);
            float sum = 0.f;
            for (int kk = 0; kk < WPL; ++kk) {
                const float e = expf(sc[j * SC_S + kk] - m);
                sc[j * SC_S + kk] = e;
                sum += e;
            }
            const float inv = 1.f / sum;
            for (int kk = 0; kk < WPL; ++kk) sc[j * SC_S + kk] *= inv;
        } else if (tid == WPL) {
            float m = -1e30f;
            for (int jj = 0; jj < WPL; ++jj) m = fmaxf(m, ts[jj]);
            float sum = 0.f;
            for (int jj = 0; jj < WPL; ++jj) { const float e = expf(ts[jj] - m); tw[jj] = e; sum += e; }
            const float inv = 1.f / sum;
            for (int jj = 0; jj < WPL; ++jj) tw[jj] *= inv;
        }
        __syncthreads();
        if (tid < WPL) {
            const int kk = tid;
            float c = 0.f;
            for (int jj = 0; jj < WPL; ++jj) c += tw[jj] * msk[jj] * sc[jj * SC_S + kk];
            cw[kk] = c;
        }
        __syncthreads();
        if (tid < DPH) {
            float acc = 0.f;
            for (int kk = 0; kk < WPL; ++kk) acc += cw[kk] * vs[kk * QKV_S + tid];
            line_e[line * AD + h * DPH + tid] = acc * mls;
        }
        __syncthreads();
    }
}

__launch_bounds__(256, 2)
__global__ void gemm_qkv(const float* __restrict__ Asrc,
                         const int* __restrict__ docs,
                         const float* __restrict__ emb,
                         const float* __restrict__ W0, const float* __restrict__ W1,
                         const float* __restrict__ W2,
                         const float* __restrict__ B0, const float* __restrict__ B1,
                         const float* __restrict__ B2,
                         float* __restrict__ C, int M, int K)
{
    __shared__ __align__(16) float As[32][132];
    __shared__ __align__(16) float Bs[32][132];

    const int tid = threadIdx.x;
    const int row0 = blockIdx.x * 128;
    const int n0 = blockIdx.y * 128;
    const int tc = tid & 15, tr = tid >> 4;

    float acc[2][2][4][4];
    #pragma unroll
    for (int a = 0; a < 2; ++a)
        #pragma unroll
        for (int b = 0; b < 2; ++b)
            #pragma unroll
            for (int c = 0; c < 4; ++c)
                #pragma unroll
                for (int d = 0; d < 4; ++d) acc[a][b][c][d] = 0.f;

    const int ma = tid & 127;
    const int kq = tid >> 7;
    const float* arow;
    if (docs) arow = emb + (size_t)docs[row0 + ma] * EMBD;
    else      arow = Asrc + (size_t)(row0 + ma) * K;

    const int gcol = n0 + ma;
    const int p = gcol / 400;
    const int ccol = gcol - p * 400;
    const float* Wp = (p == 0) ? W0 : (p == 1) ? W1 : W2;
    const bool colv = gcol < NCOLS;

    const int nk = (K + 31) >> 5;
    for (int ck = 0; ck < nk; ++ck) {
        const int k0 = ck * 32;
        #pragma unroll
        for (int f = 0; f < 4; ++f) {
            const int kl = kq * 16 + f * 4;
            const int kg = k0 + kl;
            float4 v = make_float4(0.f, 0.f, 0.f, 0.f);
            if (kg < K) v = *(const float4*)(arow + kg);
            As[kl + 0][ma] = v.x;
            As[kl + 1][ma] = v.y;
            As[kl + 2][ma] = v.z;
            As[kl + 3][ma] = v.w;
        }
        #pragma unroll
        for (int i = 0; i < 16; ++i) {
            const int kl = kq * 16 + i;
            const int kg = k0 + kl;
            float v = 0.f;
            if (colv && kg < K) v = Wp[(size_t)kg * 400 + ccol];
            Bs[kl][ma] = v;
        }
        __syncthreads();

        #pragma unroll 8
        for (int k = 0; k < 32; ++k) {
            const float4 a0 = *(const float4*)&As[k][tr * 4];
            const float4 a1 = *(const float4*)&As[k][64 + tr * 4];
            const float4 b0 = *(const float4*)&Bs[k][tc * 4];
            const float4 b1 = *(const float4*)&Bs[k][64 + tc * 4];
            const float ar[2][4] = {{a0.x, a0.y, a0.z, a0.w}, {a1.x, a1.y, a1.z, a1.w}};
            const float br[2][4] = {{b0.x, b0.y, b0.z, b0.w}, {b1.x, b1.y, b1.z, b1.w}};
            #pragma unroll
            for (int im = 0; im < 2; ++im)
                #pragma unroll
                for (int in_ = 0; in_ < 2; ++in_)
                    #pragma unroll
                    for (int rr = 0; rr < 4; ++rr)
                        #pragma unroll
                        for (int cc = 0; cc < 4; ++cc)
                            acc[im][in_][rr][cc] += ar[im][rr] * br[in_][cc];
        }
        __syncthreads();
    }

    #pragma unroll
    for (int in_ = 0; in_ < 2; ++in_) {
        const int ncol = n0 + in_ * 64 + tc * 4;
        if (ncol >= NCOLS) continue;
        const int pj = ncol / 400;
        const int cj = ncol - pj * 400;
        const float* Bp = (pj == 0) ? B0 : (pj == 1) ? B1 : B2;
        const float4 bv = *(const float4*)(Bp + cj);
        #pragma unroll
        for (int im = 0; im < 2; ++im) {
            #pragma unroll
            for (int rr = 0; rr < 4; ++rr) {
                const int row = row0 + im * 64 + tr * 4 + rr;
                float4 o;
                o.x = elu(acc[im][in_][rr][0] + bv.x);
                o.y = elu(acc[im][in_][rr][1] + bv.y);
                o.z = elu(acc[im][in_][rr][2] + bv.z);
                o.w = elu(acc[im][in_][rr][3] + bv.w);
                *(float4*)(C + (size_t)row * NCOLS + ncol) = o;
            }
        }
    }
}

__global__ void logits_kernel(const float* __restrict__ doc_e,
                              const float* __restrict__ fc1_w, const float* __restrict__ fc1_b,
                              const float* __restrict__ fc2_w, const float* __restrict__ fc2_b,
                              float* __restrict__ out)
{
    int o = blockIdx.x * blockDim.x + threadIdx.x;
    if (o >= BATCH * 582) return;
    int b = o / 582, jj = o - b * 582;
    const float* de = doc_e + b * AD;
    float acc;
    if (jj < 70) {
        acc = fc1_b[jj];
        for (int k = 0; k < AD; ++k) acc += de[k] * fc1_w[k * 70 + jj];
    } else {
        int j2 = jj - 70;
        acc = fc2_b[j2];
        for (int k = 0; k < AD; ++k) acc += de[k] * fc2_w[k * 512 + j2];
    }
    out[o] = acc;
}

// ---------------------------------------------------------------------------
extern "C" void kernel_launch(void* const* d_in, const int* in_sizes, int n_in,
                              void* d_out, int out_size, void* d_ws, size_t ws_size,
                              hipStream_t stream) {
    const int*   docs  = (const int*)  d_in[0];
    const float* emb   = (const float*)d_in[1];
    const float* wq_w  = (const float*)d_in[2];
    const float* wq_b  = (const float*)d_in[3];
    const float* wk_w  = (const float*)d_in[4];
    const float* wk_b  = (const float*)d_in[5];
    const float* wv_w  = (const float*)d_in[6];
    const float* wv_b  = (const float*)d_in[7];
    const float* w_tgt = (const float*)d_in[8];
    const float* lq_w  = (const float*)d_in[9];
    const float* lq_b  = (const float*)d_in[10];
    const float* lk_w  = (const float*)d_in[11];
    const float* lk_b  = (const float*)d_in[12];
    const float* lv_w  = (const float*)d_in[13];
    const float* lv_b  = (const float*)d_in[14];
    const float* l_tgt = (const float*)d_in[15];
    const float* fc1_w = (const float*)d_in[16];
    const float* fc1_b = (const float*)d_in[17];
    const float* fc2_w = (const float*)d_in[18];
    const float* fc2_b = (const float*)d_in[19];
    float* out = (float*)d_out;
    float* ws = (float*)d_ws;

    const long O_LINE_E = 0;
    const long O_MASK_L = 819200;
    const long O_DOC_E  = 821248;
    const long O_BIAS_W = 827648;
    const long O_BIAS_L = 828928;
    const long O_EMB_H  = 830208;
    const long O_WTW_H  = 10430208;
    const long O_WTL_H  = 10839808;
    const long O_LE_H   = 11372288;
    const long O_R      = 12224256;

    const long LINE_QKV_FL = (long)NLINES * NCOLS;    // 2457600
    long ws_fl = (long)(ws_size / 4);
    long Rcap = ws_fl - O_R;

    if (Rcap >= LINE_QKV_FL) {
        // ================= MFMA fast path (fused word level) =================
        float* line_e = ws + O_LINE_E;
        float* mask_l = ws + O_MASK_L;
        float* doc_e  = ws + O_DOC_E;
        float* bias_w = ws + O_BIAS_W;
        float* bias_l = ws + O_BIAS_L;
        bf16* embp = (bf16*)(ws + O_EMB_H);
        bf16* wtwp = (bf16*)(ws + O_WTW_H);
        bf16* wtlp = (bf16*)(ws + O_WTL_H);
        bf16* lep  = (bf16*)(ws + O_LE_H);
        float* R   = ws + O_R;

        split_rows_packed<<<(30000L * 320 + 255) / 256, 256, 0, stream>>>(emb, embp, 30000, 300, 320);
        split_wt_packed<<<((long)NPAD * 320 + 255) / 256, 256, 0, stream>>>(wq_w, wk_w, wv_w,
                                                                            wq_b, wk_b, wv_b,
                                                                            wtwp, bias_w, 300, 320);
        split_wt_packed<<<((long)NPAD * 416 + 255) / 256, 256, 0, stream>>>(lq_w, lk_w, lv_w,
                                                                            lq_b, lk_b, lv_b,
                                                                            wtlp, bias_l, 400, 416);

        fused_word<<<NLINES, 512, 0, stream>>>(embp, docs, wtwp, bias_w, w_tgt,
                                               line_e, mask_l);

        split_rows_packed<<<((long)NLINES * 416 + 255) / 256, 256, 0, stream>>>(line_e, lep,
                                                                                NLINES, 400, 416);
        dim3 g2(10, NLINES / 128);
        mfma_gemm<<<g2, 256, 0, stream>>>(lep, nullptr, wtlp, bias_l, R, 416, 0);
        line_attn2<<<BATCH * NH, 256, 0, stream>>>(R, R + 400, R + 800,
                                                   (long)LPD * NCOLS, (long)DPH, (long)NCOLS,
                                                   l_tgt, mask_l, doc_e);
        logits_kernel<<<(BATCH * 582 + 255) / 256, 256, 0, stream>>>(doc_e, fc1_w, fc1_b,
                                                                     fc2_w, fc2_b, out);
    } else {
        // ================= fp32 fallback =================
        const long F_FIXED = 827648;
        const long PER_LINE_FL = (long)WPL * NCOLS;
        float* line_e = ws;
        float* mask_l = ws + 819200;
        float* doc_e  = ws + 821248;
        float* R      = ws + F_FIXED;
        long Rcap2 = ws_fl - F_FIXED;

        long maxl = Rcap2 / PER_LINE_FL;
        if (maxl > NLINES) maxl = NLINES;
        long maxl4 = (maxl / 4) * 4;
        int nc = (int)((NLINES + maxl4 - 1) / maxl4);
        int chunk = (int)((NLINES + nc - 1) / nc);
        chunk = ((chunk + 3) / 4) * 4;

        for (int c0 = 0; c0 < NLINES; c0 += chunk) {
            int cl = NLINES - c0 < chunk ? NLINES - c0 : chunk;
            dim3 g1((cl * 32) / 128, 10);
            gemm_qkv<<<g1, 256, 0, stream>>>(nullptr, docs + (size_t)c0 * WPL, emb,
                                             wq_w, wk_w, wv_w, wq_b, wk_b, wv_b,
                                             R, cl * 32, EMBD);
            word_attn<<<cl, 256, 0, stream>>>(R, docs + (size_t)c0 * WPL, w_tgt,
                                              line_e + (size_t)c0 * AD, mask_l + c0);
        }
        dim3 g2(16, 10);
        gemm_qkv<<<g2, 256, 0, stream>>>(line_e, nullptr, emb,
                                         lq_w, lk_w, lv_w, lq_b, lk_b, lv_b,
                                         R, NLINES, AD);
        line_attn2<<<BATCH * NH, 256, 0, stream>>>(R, R + 400, R + 800,
                                                   (long)LPD * NCOLS, (long)DPH, (long)NCOLS,
                                                   l_tgt, mask_l, doc_e);
        logits_kernel<<<(BATCH * 582 + 255) / 256, 256, 0, stream>>>(doc_e, fc1_w, fc1_b,
                                                                     fc2_w, fc2_b, out);
    }
}